// Round 1
// baseline (1017.391 us; speedup 1.0000x reference)
//
#include <hip/hip_runtime.h>
#include <hip/hip_bf16.h>
#include <math.h>

#define HH 1024
#define AA 512
#define TV 4096
#define NB 32

typedef __bf16 v8bf __attribute__((ext_vector_type(8)));
typedef float v4f __attribute__((ext_vector_type(4)));

__device__ __forceinline__ float fast_tanh(float x) {
  float e = __expf(2.0f * x);
  return 1.0f - 2.0f / (e + 1.0f);   // x>>0: e=inf -> 1; x<<0: e=0 -> -1
}

// K0: W_T[n][k] (bf16) = W_V[k][n]  -- transpose + convert once per launch
__global__ void k_wt(const float* __restrict__ wv, __bf16* __restrict__ wt) {
  int idx = blockIdx.x * 256 + threadIdx.x;   // 0 .. 512*1024-1
  int k = idx >> 9;
  int n = idx & 511;
  wt[(size_t)n * HH + k] = (__bf16)wv[idx];
}

// K1: qb[b][a] = sum_h query[b][h]*W_Q[h][a] + bias[a]   (atomic partials over 4 h-chunks)
__global__ void k_qb(const float* __restrict__ query, const float* __restrict__ wq,
                     const float* __restrict__ bias, float* __restrict__ qb) {
  int b = blockIdx.x, hc = blockIdx.y;
  int a = threadIdx.x;                 // 512 threads = all of A
  __shared__ float ql[256];
  if (a < 256) ql[a] = query[b * HH + hc * 256 + a];
  __syncthreads();
  float s = (hc == 0) ? bias[a] : 0.0f;
  const float* w = wq + (size_t)(hc * 256) * AA + a;
  #pragma unroll 8
  for (int h = 0; h < 256; ++h) s += ql[h] * w[(size_t)h * AA];
  atomicAdd(&qb[b * AA + a], s);
}

// K2: fused  scores[b][t] = fc . tanh(value[b][t]*W_V + qb[b])
// Tile: BM=128 (t), BN=512 (all of A), BK=32. 8 waves; wave grid 2(M)x4(N),
// each wave 64x128 = 4x8 mfma_16x16x32 tiles = 128 acc VGPRs.
#define BM 128
#define BK 32
#define LDA 40   // LDS row stride in elements (80B = 5*16B -> conflict-free quad reads)

__launch_bounds__(512, 1)
__global__ void k_score(const float* __restrict__ value, const __bf16* __restrict__ wt,
                        const float* __restrict__ qb, const float* __restrict__ fc,
                        float* __restrict__ scores) {
  __shared__ __align__(16) __bf16 As[BM * LDA];    // 10.0 KB
  __shared__ __align__(16) __bf16 Bs[AA * LDA];    // 40.0 KB
  __shared__ float s_red[BM * 4];                  //  2.0 KB

  const int tid  = threadIdx.x;
  const int lane = tid & 63, wave = tid >> 6;
  const int quad = lane >> 4, l15 = lane & 15;
  const int wm = wave & 1, wn = wave >> 1;

  const size_t m0 = (size_t)blockIdx.x * BM;
  const float* Ag = value + m0 * HH;

  const int am = tid >> 2, aq = tid & 3;   // A staging: row am, 8-elem chunk aq

  v4f acc[4][8];
  #pragma unroll
  for (int i = 0; i < 4; ++i)
    #pragma unroll
    for (int n = 0; n < 8; ++n) { acc[i][n][0]=0.f; acc[i][n][1]=0.f; acc[i][n][2]=0.f; acc[i][n][3]=0.f; }

  for (int kk = 0; kk < HH; kk += BK) {
    // Stage A: 128x32 fp32 -> bf16 (2 x float4 per thread)
    const float* ap = Ag + (size_t)am * HH + kk + aq * 8;
    float4 f0 = *(const float4*)ap;
    float4 f1 = *(const float4*)(ap + 4);
    v8bf av;
    av[0]=(__bf16)f0.x; av[1]=(__bf16)f0.y; av[2]=(__bf16)f0.z; av[3]=(__bf16)f0.w;
    av[4]=(__bf16)f1.x; av[5]=(__bf16)f1.y; av[6]=(__bf16)f1.z; av[7]=(__bf16)f1.w;
    *(v8bf*)&As[am * LDA + aq * 8] = av;
    // Stage B: 512x32 bf16 from W_T (k-contiguous), coalesced 16B chunks
    #pragma unroll
    for (int j = 0; j < 4; ++j) {
      int c = j * 512 + tid;
      int n = c >> 2, off = c & 3;
      uint4 d = *(const uint4*)(wt + (size_t)n * HH + kk + off * 8);
      *(uint4*)&Bs[n * LDA + off * 8] = d;
    }
    __syncthreads();
    v8bf af[4], bfr[8];
    #pragma unroll
    for (int i = 0; i < 4; ++i)
      af[i] = *(v8bf*)&As[(wm * 64 + i * 16 + l15) * LDA + quad * 8];
    #pragma unroll
    for (int n = 0; n < 8; ++n)
      bfr[n] = *(v8bf*)&Bs[(wn * 128 + n * 16 + l15) * LDA + quad * 8];
    #pragma unroll
    for (int i = 0; i < 4; ++i)
      #pragma unroll
      for (int n = 0; n < 8; ++n)
        acc[i][n] = __builtin_amdgcn_mfma_f32_16x16x32_bf16(af[i], bfr[n], acc[i][n], 0, 0, 0);
    __syncthreads();
  }

  // Epilogue: s[row] = sum_col fc[col]*tanh(acc + qb[b][col]); C/D: row=quad*4+reg, col=l15
  const int bb = blockIdx.x >> 5;          // 4096/128 = 32 tiles per batch
  const int t0 = (blockIdx.x & 31) * BM;
  float fcl[8], qbl[8];
  #pragma unroll
  for (int n = 0; n < 8; ++n) {
    int col = wn * 128 + n * 16 + l15;
    fcl[n] = fc[col];
    qbl[n] = qb[bb * AA + col];
  }
  #pragma unroll
  for (int i = 0; i < 4; ++i) {
    #pragma unroll
    for (int j = 0; j < 4; ++j) {
      float p = 0.0f;
      #pragma unroll
      for (int n = 0; n < 8; ++n)
        p += fcl[n] * fast_tanh(acc[i][n][j] + qbl[n]);
      p += __shfl_xor(p, 1);
      p += __shfl_xor(p, 2);
      p += __shfl_xor(p, 4);
      p += __shfl_xor(p, 8);
      if (l15 == 0) {
        int row = wm * 64 + i * 16 + quad * 4 + j;
        s_red[row * 4 + wn] = p;
      }
    }
  }
  __syncthreads();
  if (tid < BM) {
    float s = s_red[tid * 4 + 0] + s_red[tid * 4 + 1] + s_red[tid * 4 + 2] + s_red[tid * 4 + 3];
    scores[(size_t)bb * TV + t0 + tid] = s;
  }
}

// K3: softmax over Tv per batch (in place)
__global__ void k_softmax(float* __restrict__ scores) {
  int b = blockIdx.x;
  int tid = threadIdx.x;                 // 256
  float* s = scores + (size_t)b * TV;
  float local[16];
  float mx = -1e30f;
  #pragma unroll
  for (int i = 0; i < 16; ++i) { local[i] = s[i * 256 + tid]; mx = fmaxf(mx, local[i]); }
  __shared__ float red[8];
  #pragma unroll
  for (int o = 32; o > 0; o >>= 1) mx = fmaxf(mx, __shfl_xor(mx, o));
  int wv = tid >> 6;
  if ((tid & 63) == 0) red[wv] = mx;
  __syncthreads();
  mx = fmaxf(fmaxf(red[0], red[1]), fmaxf(red[2], red[3]));
  float sum = 0.0f;
  #pragma unroll
  for (int i = 0; i < 16; ++i) { local[i] = __expf(local[i] - mx); sum += local[i]; }
  #pragma unroll
  for (int o = 32; o > 0; o >>= 1) sum += __shfl_xor(sum, o);
  if ((tid & 63) == 0) red[4 + wv] = sum;
  __syncthreads();
  float inv = 1.0f / (red[4] + red[5] + red[6] + red[7]);
  #pragma unroll
  for (int i = 0; i < 16; ++i) s[i * 256 + tid] = local[i] * inv;
}

// K4: partial context over t-chunks: partial[b][tc][h] = sum_{t in chunk} align*value
__global__ void k_ctx_partial(const float* __restrict__ value, const float* __restrict__ align,
                              float* __restrict__ partial, int TC, int NC) {
  int tc = blockIdx.x, b = blockIdx.y;
  int tid = threadIdx.x;                 // 256; each thread covers 4 h (float4)
  extern __shared__ float al[];
  for (int i = tid; i < TC; i += 256) al[i] = align[(size_t)b * TV + (size_t)tc * TC + i];
  __syncthreads();
  const float* vp = value + ((size_t)b * TV + (size_t)tc * TC) * HH + tid * 4;
  float ax = 0.f, ay = 0.f, az = 0.f, aw = 0.f;
  for (int t = 0; t < TC; ++t) {
    float4 v = *(const float4*)(vp + (size_t)t * HH);
    float a = al[t];
    ax = fmaf(a, v.x, ax); ay = fmaf(a, v.y, ay);
    az = fmaf(a, v.z, az); aw = fmaf(a, v.w, aw);
  }
  float4 o; o.x = ax; o.y = ay; o.z = az; o.w = aw;
  *(float4*)&partial[((size_t)(b * NC + tc)) * HH + tid * 4] = o;
}

// K5: context[b][h] = sum_tc partial
__global__ void k_ctx_reduce(const float* __restrict__ partial, float* __restrict__ out, int NC) {
  int g = blockIdx.x * 256 + threadIdx.x;  // 0..32767
  int b = g >> 10, h = g & 1023;
  float s = 0.0f;
  for (int c = 0; c < NC; ++c) s += partial[((size_t)(b * NC + c)) * HH + h];
  out[g] = s;
}

extern "C" void kernel_launch(void* const* d_in, const int* in_sizes, int n_in,
                              void* d_out, int out_size, void* d_ws, size_t ws_size,
                              hipStream_t stream) {
  const float* query = (const float*)d_in[0];
  const float* value = (const float*)d_in[1];
  const float* wq    = (const float*)d_in[2];
  const float* wv    = (const float*)d_in[3];
  const float* bias  = (const float*)d_in[4];
  const float* fc    = (const float*)d_in[5];
  float* out = (float*)d_out;

  char* ws = (char*)d_ws;
  __bf16* wt    = (__bf16*)ws;                                  // 1 MB
  float*  qb    = (float*)(ws + (1 << 20));                     // 64 KB
  float*  scores= (float*)(ws + (1 << 20) + (1 << 16));         // 512 KB
  size_t  base  = (1 << 20) + (1 << 16) + (1 << 19);
  float*  partial = (float*)(ws + base);

  int NC = 32;                                                  // t-chunks for context pass
  while (NC > 1 && base + (size_t)NB * NC * HH * 4 > ws_size) NC >>= 1;
  int TC = TV / NC;

  hipMemsetAsync(qb, 0, NB * AA * sizeof(float), stream);
  k_wt<<<2048, 256, 0, stream>>>(wv, wt);
  k_qb<<<dim3(NB, 4), 512, 0, stream>>>(query, wq, bias, qb);
  k_score<<<(NB * TV) / BM, 512, 0, stream>>>(value, wt, qb, fc, scores);
  k_softmax<<<NB, 256, 0, stream>>>(scores);
  k_ctx_partial<<<dim3(NC, NB), 256, TC * sizeof(float), stream>>>(value, scores, partial, TC, NC);
  k_ctx_reduce<<<(NB * HH) / 256, 256, 0, stream>>>(partial, out, NC);
}

// Round 2
// 942.454 us; speedup vs baseline: 1.0795x; 1.0795x over previous
//
#include <hip/hip_runtime.h>
#include <hip/hip_bf16.h>
#include <math.h>

#define HH 1024
#define AA 512
#define TV 4096
#define NB 32

typedef __bf16 v8bf __attribute__((ext_vector_type(8)));
typedef float v4f __attribute__((ext_vector_type(4)));

__device__ __forceinline__ float fast_tanh(float x) {
  float e = __expf(2.0f * x);
  return 1.0f - 2.0f / (e + 1.0f);   // x>>0: e=inf -> 1; x<<0: e=0 -> -1
}

__device__ __forceinline__ void load_lds16(const void* g, void* l) {
  __builtin_amdgcn_global_load_lds(
      (const __attribute__((address_space(1))) void*)g,
      (__attribute__((address_space(3))) void*)l, 16, 0, 0);
}

// K0: wt2[n][g*32 + c*8 + j] = W_V[g*32 + (c^sw(n))*8 + j][n], sw(n)=(n>>1)&3.
// Pre-swizzled bf16 W^T so k_score can stage B with global_load_lds (linear LDS
// placement) yet read fragments conflict-free (2 lanes/bank).
__global__ void k_wt(const float* __restrict__ wv, __bf16* __restrict__ wt2) {
  int idx = blockIdx.x * 256 + threadIdx.x;   // 512 rows * 128 chunks-of-8
  int n = idx >> 7;
  int cl = idx & 127;
  int g = cl >> 2, c = cl & 3;
  int sw = (n >> 1) & 3;
  int ks = g * 32 + ((c ^ sw) & 3) * 8;
  v8bf o;
  #pragma unroll
  for (int j = 0; j < 8; ++j) o[j] = (__bf16)wv[(size_t)(ks + j) * AA + n];
  *(v8bf*)&wt2[(size_t)n * HH + g * 32 + c * 8] = o;
}

// K1: qb[b][a] = sum_h query[b][h]*W_Q[h][a] + bias[a]
__global__ void k_qb(const float* __restrict__ query, const float* __restrict__ wq,
                     const float* __restrict__ bias, float* __restrict__ qb) {
  int b = blockIdx.x, hc = blockIdx.y;
  int a = threadIdx.x;                 // 512 threads = all of A
  __shared__ float ql[256];
  if (a < 256) ql[a] = query[b * HH + hc * 256 + a];
  __syncthreads();
  float s = (hc == 0) ? bias[a] : 0.0f;
  const float* w = wq + (size_t)(hc * 256) * AA + a;
  #pragma unroll 8
  for (int h = 0; h < 256; ++h) s += ql[h] * w[(size_t)h * AA];
  atomicAdd(&qb[b * AA + a], s);
}

// K2: scores[b][t] = fc . tanh(value[b][t]*W_V + qb[b])
// BM=64, BN=512(all A), BK=32; 256 threads = 4 waves, each 64x128 (4x8 tiles).
#define BM 64
#define BK 32
#define LDA 40   // As row stride (80B) -> 2-way (free) frag reads

__launch_bounds__(256, 2)
__global__ void k_score(const float* __restrict__ value, const __bf16* __restrict__ wt2,
                        const float* __restrict__ qb, const float* __restrict__ fc,
                        float* __restrict__ scores) {
  __shared__ __align__(16) __bf16 As[BM * LDA];    //  5.0 KB
  __shared__ __align__(16) __bf16 Bs[AA * BK];     // 32.0 KB, unpadded (global_load_lds), swizzled
  __shared__ float s_red[BM * 4];                  //  1.0 KB

  const int tid  = threadIdx.x;
  const int lane = tid & 63, w = tid >> 6;
  const int quad = lane >> 4, l15 = lane & 15;
  const int swl  = (l15 >> 1) & 3;
  const int bcol = ((quad ^ swl) & 3) * 8;     // swizzled chunk for B frag

  const size_t m0 = (size_t)blockIdx.x * BM;
  const float* Ag = value + m0 * HH;

  const int ar = tid >> 2, ac = (tid & 3) * 8;       // A staging: 64 rows x 4 chunks-of-8
  const int brow_l = lane >> 2, bchunk = (lane & 3) * 8;  // B staging lane roles

  v4f acc[4][8];
  #pragma unroll
  for (int i = 0; i < 4; ++i)
    #pragma unroll
    for (int n = 0; n < 8; ++n) { acc[i][n][0]=0.f; acc[i][n][1]=0.f; acc[i][n][2]=0.f; acc[i][n][3]=0.f; }

  const float* ap0 = Ag + (size_t)ar * HH + ac;
  float4 a0 = *(const float4*)ap0;
  float4 a1 = *(const float4*)(ap0 + 4);

  for (int kk = 0; kk < HH; kk += BK) {
    __syncthreads();                       // prev MFMA done reading LDS
    // B: async global->LDS, 8 x 1KB per wave (32KB total)
    #pragma unroll
    for (int i = 0; i < 8; ++i) {
      int r0 = w * 128 + i * 16;
      load_lds16(wt2 + (size_t)(r0 + brow_l) * HH + kk + bchunk, (void*)&Bs[r0 * BK]);
    }
    // A: prefetched regs -> bf16 -> LDS
    {
      v8bf av;
      av[0]=(__bf16)a0.x; av[1]=(__bf16)a0.y; av[2]=(__bf16)a0.z; av[3]=(__bf16)a0.w;
      av[4]=(__bf16)a1.x; av[5]=(__bf16)a1.y; av[6]=(__bf16)a1.z; av[7]=(__bf16)a1.w;
      *(v8bf*)&As[ar * LDA + ac] = av;
    }
    __syncthreads();                       // drains vmcnt(0): Bs + As visible
    // A prefetch for next iter rides under the MFMA phase
    if (kk + BK < HH) {
      const float* apn = Ag + (size_t)ar * HH + kk + BK + ac;
      a0 = *(const float4*)apn;
      a1 = *(const float4*)(apn + 4);
    }
    v8bf af[4], bfr[8];
    #pragma unroll
    for (int mt = 0; mt < 4; ++mt)
      af[mt] = *(v8bf*)&As[(mt * 16 + l15) * LDA + quad * 8];
    #pragma unroll
    for (int nt = 0; nt < 8; ++nt) {
      int n = w * 128 + nt * 16 + l15;
      bfr[nt] = *(v8bf*)&Bs[n * BK + bcol];
    }
    #pragma unroll
    for (int mt = 0; mt < 4; ++mt)
      #pragma unroll
      for (int nt = 0; nt < 8; ++nt)
        acc[mt][nt] = __builtin_amdgcn_mfma_f32_16x16x32_bf16(af[mt], bfr[nt], acc[mt][nt], 0, 0, 0);
  }

  // Epilogue. C/D: row = quad*4+reg, col = l15.
  const int bb = blockIdx.x >> 6;          // TV/BM = 64 tiles per batch
  const int t0 = (blockIdx.x & 63) * BM;
  float fcl[8], qbl[8];
  #pragma unroll
  for (int nt = 0; nt < 8; ++nt) {
    int col = w * 128 + nt * 16 + l15;
    fcl[nt] = fc[col];
    qbl[nt] = qb[bb * AA + col];
  }
  #pragma unroll
  for (int mt = 0; mt < 4; ++mt) {
    #pragma unroll
    for (int j = 0; j < 4; ++j) {
      float p = 0.0f;
      #pragma unroll
      for (int nt = 0; nt < 8; ++nt)
        p += fcl[nt] * fast_tanh(acc[mt][nt][j] + qbl[nt]);
      p += __shfl_xor(p, 1);
      p += __shfl_xor(p, 2);
      p += __shfl_xor(p, 4);
      p += __shfl_xor(p, 8);
      if (l15 == 0) s_red[(mt * 16 + quad * 4 + j) * 4 + w] = p;
    }
  }
  __syncthreads();
  if (tid < BM) {
    float s = s_red[tid * 4 + 0] + s_red[tid * 4 + 1] + s_red[tid * 4 + 2] + s_red[tid * 4 + 3];
    scores[(size_t)bb * TV + t0 + tid] = s;
  }
}

// K3: softmax over Tv per batch (in place)
__global__ void k_softmax(float* __restrict__ scores) {
  int b = blockIdx.x;
  int tid = threadIdx.x;                 // 256
  float* s = scores + (size_t)b * TV;
  float local[16];
  float mx = -1e30f;
  #pragma unroll
  for (int i = 0; i < 16; ++i) { local[i] = s[i * 256 + tid]; mx = fmaxf(mx, local[i]); }
  __shared__ float red[8];
  #pragma unroll
  for (int o = 32; o > 0; o >>= 1) mx = fmaxf(mx, __shfl_xor(mx, o));
  int wv = tid >> 6;
  if ((tid & 63) == 0) red[wv] = mx;
  __syncthreads();
  mx = fmaxf(fmaxf(red[0], red[1]), fmaxf(red[2], red[3]));
  float sum = 0.0f;
  #pragma unroll
  for (int i = 0; i < 16; ++i) { local[i] = __expf(local[i] - mx); sum += local[i]; }
  #pragma unroll
  for (int o = 32; o > 0; o >>= 1) sum += __shfl_xor(sum, o);
  if ((tid & 63) == 0) red[4 + wv] = sum;
  __syncthreads();
  float inv = 1.0f / (red[4] + red[5] + red[6] + red[7]);
  #pragma unroll
  for (int i = 0; i < 16; ++i) s[i * 256 + tid] = local[i] * inv;
}

// K4: partial context over t-chunks
__global__ void k_ctx_partial(const float* __restrict__ value, const float* __restrict__ align,
                              float* __restrict__ partial, int TC, int NC) {
  int tc = blockIdx.x, b = blockIdx.y;
  int tid = threadIdx.x;                 // 256; each thread covers 4 h (float4)
  extern __shared__ float al[];
  for (int i = tid; i < TC; i += 256) al[i] = align[(size_t)b * TV + (size_t)tc * TC + i];
  __syncthreads();
  const float* vp = value + ((size_t)b * TV + (size_t)tc * TC) * HH + tid * 4;
  float ax = 0.f, ay = 0.f, az = 0.f, aw = 0.f;
  #pragma unroll 8
  for (int t = 0; t < TC; ++t) {
    float4 v = *(const float4*)(vp + (size_t)t * HH);
    float a = al[t];
    ax = fmaf(a, v.x, ax); ay = fmaf(a, v.y, ay);
    az = fmaf(a, v.z, az); aw = fmaf(a, v.w, aw);
  }
  float4 o; o.x = ax; o.y = ay; o.z = az; o.w = aw;
  *(float4*)&partial[((size_t)(b * NC + tc)) * HH + tid * 4] = o;
}

// K5: context[b][h] = sum_tc partial
__global__ void k_ctx_reduce(const float* __restrict__ partial, float* __restrict__ out, int NC) {
  int g = blockIdx.x * 256 + threadIdx.x;  // 0..32767
  int b = g >> 10, h = g & 1023;
  float s = 0.0f;
  for (int c = 0; c < NC; ++c) s += partial[((size_t)(b * NC + c)) * HH + h];
  out[g] = s;
}

extern "C" void kernel_launch(void* const* d_in, const int* in_sizes, int n_in,
                              void* d_out, int out_size, void* d_ws, size_t ws_size,
                              hipStream_t stream) {
  const float* query = (const float*)d_in[0];
  const float* value = (const float*)d_in[1];
  const float* wq    = (const float*)d_in[2];
  const float* wv    = (const float*)d_in[3];
  const float* bias  = (const float*)d_in[4];
  const float* fc    = (const float*)d_in[5];
  float* out = (float*)d_out;

  char* ws = (char*)d_ws;
  __bf16* wt2   = (__bf16*)ws;                                  // 1 MB
  float*  qb    = (float*)(ws + (1 << 20));                     // 64 KB
  float*  scores= (float*)(ws + (1 << 20) + (1 << 16));         // 512 KB
  size_t  base  = (1 << 20) + (1 << 16) + (1 << 19);
  float*  partial = (float*)(ws + base);

  int NC = 64;                                                  // t-chunks for context pass
  while (NC > 1 && base + (size_t)NB * NC * HH * 4 > ws_size) NC >>= 1;
  int TC = TV / NC;

  hipMemsetAsync(qb, 0, NB * AA * sizeof(float), stream);
  k_wt<<<256, 256, 0, stream>>>(wv, wt2);
  k_qb<<<dim3(NB, 4), 512, 0, stream>>>(query, wq, bias, qb);
  k_score<<<(NB * TV) / BM, 256, 0, stream>>>(value, wt2, qb, fc, scores);
  k_softmax<<<NB, 256, 0, stream>>>(scores);
  k_ctx_partial<<<dim3(NC, NB), 256, TC * sizeof(float), stream>>>(value, scores, partial, TC, NC);
  k_ctx_reduce<<<(NB * HH) / 256, 256, 0, stream>>>(partial, out, NC);
}